// Round 4
// baseline (194.798 us; speedup 1.0000x reference)
//
#include <hip/hip_runtime.h>

#define NT 2000
#define NB 256
#define NF 5
#define NS 500
#define LOG0   (-1e30f)
#define LOG2E  1.44269504088896340736f
#define LN2F   0.69314718055994530942f
#define RSTRIDE 2024               // LDS fallback row stride
#define WROW 2000                  // global weight row stride (floats)
#define WBLK (4 * WROW)            // floats per batch
#define WS_NEEDED ((size_t)NB * WBLK * 4 + (size_t)NB * 4)

// Cross-lane shift-up-by-1 via DPP wave_shr1 (0x138): lane n gets lane n-1,
// lane 0 gets 0 (old=0). VALU-speed, no LDS pipe, ~2cy latency.
__device__ __forceinline__ float shift_up1(float v) {
    int r = __builtin_amdgcn_update_dpp(0, __float_as_int(v), 0x138, 0xF, 0xF, false);
    return __int_as_float(r);
}

#define STEP(W0, W1, W2) do {                 \
        const float sh = shift_up1(p2);       \
        p2 = fmaf(p1, (W2), p2);              \
        p1 = fmaf(p0, (W1), p1);              \
        p0 = fmaf(sh * adj, (W0), p0);        \
    } while (0)

// ---------------- kernel 1: weights + stay-sum precompute ----------------
__global__ __launch_bounds__(256) void prep_kernel(
    const float* __restrict__ x,   // (NT, NB, NF)
    float*       __restrict__ W,   // (NB, 4, WROW)
    float*       __restrict__ Csum)// (NB,)
{
    __shared__ float red[256];
    const int b = blockIdx.x, tid = threadIdx.x;
    float* wb = W + (size_t)b * WBLK;
    float csum = 0.f;
    for (int t = tid; t < NT; t += 256) {
        const float* xp = x + (size_t)t * (NB * NF) + b * NF;
        const float x4 = xp[4];
        wb[0 * WROW + t] = __builtin_amdgcn_exp2f((xp[0] - x4) * LOG2E);
        wb[1 * WROW + t] = __builtin_amdgcn_exp2f((xp[1] - x4) * LOG2E);
        wb[2 * WROW + t] = __builtin_amdgcn_exp2f((xp[2] - x4) * LOG2E);
        wb[3 * WROW + t] = __builtin_amdgcn_exp2f((xp[3] - x4) * LOG2E);
        csum += x4;
    }
    red[tid] = csum;
    __syncthreads();
    for (int off = 128; off > 0; off >>= 1) {
        if (tid < off) red[tid] += red[tid + off];
        __syncthreads();
    }
    if (tid == 0) Csum[b] = red[0];
}

// ---------------- kernel 2: the scan, weights from global ----------------
// Same structure as R3 (4 waves, 192-state span/wave, per-lane log2 scale,
// renorm/16, LDS log2-domain exchange/64) but: (a) shfl_up -> DPP, (b) weight
// reads are global dwordx4 (L1/L2-resident) -> hot loop does zero LDS traffic.
__global__ __launch_bounds__(256) void scan_kernel(
    const float* __restrict__ W,        // (NB, 4, WROW)
    const float* __restrict__ Csum,     // (NB,)
    const int*   __restrict__ seqs,     // (NB, NS)
    const int*   __restrict__ seqlens,  // (NB,)
    float*       __restrict__ out)      // (NB,)
{
    __shared__ float Gbuf[576];

    const int b    = blockIdx.x;
    const int tid  = threadIdx.x;
    const int wave = tid >> 6;
    const int lane = tid & 63;

    for (int i = tid; i < 576; i += 256) Gbuf[i] = LOG0;

    const int wbase = wave * 128 - 64;
    const int rel0 = 3 * lane;
    const int s0 = wbase + rel0, s1 = s0 + 1, s2 = s0 + 2;

    const int i0 = (s0 >= 1 && s0 <= NS) ? seqs[b * NS + s0 - 1] : 0;
    const int i1 = (s1 >= 1 && s1 <= NS) ? seqs[b * NS + s1 - 1] : 0;
    const int i2 = (s2 >= 1 && s2 <= NS) ? seqs[b * NS + s2 - 1] : 0;
    const float* wb = W + (size_t)b * WBLK;
    const float* wrow0 = wb + i0 * WROW;
    const float* wrow1 = wb + i1 * WROW;
    const float* wrow2 = wb + i2 * WROW;

    float p0 = (s0 == 0) ? 1.f : 0.f;
    float p1 = (s1 == 0) ? 1.f : 0.f;
    float p2 = (s2 == 0) ? 1.f : 0.f;
    float Lw  = 0.f;
    float adj = 1.f;

    __syncthreads();

    for (int c = 0; c < 125; ++c) {
        if (c > 0) {
            if ((c & 3) == 0) {
                __syncthreads();
                if (rel0     >= 64) Gbuf[64 + s0] = (p0 > 0.f) ? __builtin_amdgcn_logf(p0) + Lw : LOG0;
                if (rel0 + 1 >= 64) Gbuf[64 + s1] = (p1 > 0.f) ? __builtin_amdgcn_logf(p1) + Lw : LOG0;
                if (rel0 + 2 >= 64) Gbuf[64 + s2] = (p2 > 0.f) ? __builtin_amdgcn_logf(p2) + Lw : LOG0;
                __syncthreads();
                const float g0 = Gbuf[64 + s0];
                const float g1 = Gbuf[64 + s1];
                const float g2 = Gbuf[64 + s2];
                const float ref = fmaxf(fmaxf(g0, g1), g2);
                const bool alive = (ref > 0.5f * LOG0);
                int lastlive = alive ? lane : -1;
                #pragma unroll
                for (int o = 1; o < 64; o <<= 1) lastlive = max(lastlive, __shfl_xor(lastlive, o));
                float fb = __shfl(ref, (lastlive >= 0) ? lastlive : 0);
                if (lastlive < 0) fb = 0.f;
                Lw = alive ? ref : fb;
                p0 = __builtin_amdgcn_exp2f(g0 - Lw);
                p1 = __builtin_amdgcn_exp2f(g1 - Lw);
                p2 = __builtin_amdgcn_exp2f(g2 - Lw);
            } else {
                const float m = fmaxf(fmaxf(p0, p1), p2);
                if (m > 0.f) {
                    const float inv = __builtin_amdgcn_rcpf(m);
                    Lw += __builtin_amdgcn_logf(m);
                    p0 *= inv; p1 *= inv; p2 *= inv;
                }
            }
            const float Lwp = __shfl_up(Lw, 1);
            adj = __builtin_amdgcn_exp2f(fminf(Lwp - Lw, 100.f));
        }
        const int tb = c << 4;
        #pragma unroll
        for (int q = 0; q < 4; ++q) {
            const float4 wa = *reinterpret_cast<const float4*>(wrow0 + tb + 4 * q);
            const float4 wc4 = *reinterpret_cast<const float4*>(wrow1 + tb + 4 * q);
            const float4 wd = *reinterpret_cast<const float4*>(wrow2 + tb + 4 * q);
            STEP(wa.x, wc4.x, wd.x);
            STEP(wa.y, wc4.y, wd.y);
            STEP(wa.z, wc4.z, wd.z);
            STEP(wa.w, wc4.w, wd.w);
        }
    }

    __syncthreads();
    if (rel0     >= 64) Gbuf[64 + s0] = (p0 > 0.f) ? __builtin_amdgcn_logf(p0) + Lw : LOG0;
    if (rel0 + 1 >= 64) Gbuf[64 + s1] = (p1 > 0.f) ? __builtin_amdgcn_logf(p1) + Lw : LOG0;
    if (rel0 + 2 >= 64) Gbuf[64 + s2] = (p2 > 0.f) ? __builtin_amdgcn_logf(p2) + Lw : LOG0;
    __syncthreads();
    if (tid == 0) {
        const int sl = seqlens[b];
        out[b] = -(Gbuf[64 + sl] * LN2F + Csum[b]) * (1.0f / (float)NT);
    }
}

// ---------------- fallback: R3 structure + DPP (if ws too small) ----------------
__global__ __launch_bounds__(256) void ctc_fwd_fallback(
    const float* __restrict__ x,
    const int*   __restrict__ seqs,
    const int*   __restrict__ seqlens,
    float*       __restrict__ out)
{
    __shared__ __align__(16) float wtabT[4 * RSTRIDE];
    __shared__ float Gbuf[576];
    __shared__ float red[256];

    const int b    = blockIdx.x;
    const int tid  = threadIdx.x;
    const int wave = tid >> 6;
    const int lane = tid & 63;

    float csum = 0.f;
    for (int t = tid; t < NT; t += 256) {
        const float* xp = x + (size_t)t * (NB * NF) + b * NF;
        const float x4 = xp[4];
        wtabT[0 * RSTRIDE + t] = __builtin_amdgcn_exp2f((xp[0] - x4) * LOG2E);
        wtabT[1 * RSTRIDE + t] = __builtin_amdgcn_exp2f((xp[1] - x4) * LOG2E);
        wtabT[2 * RSTRIDE + t] = __builtin_amdgcn_exp2f((xp[2] - x4) * LOG2E);
        wtabT[3 * RSTRIDE + t] = __builtin_amdgcn_exp2f((xp[3] - x4) * LOG2E);
        csum += x4;
    }
    for (int i = tid; i < 576; i += 256) Gbuf[i] = LOG0;
    red[tid] = csum;
    __syncthreads();
    for (int off = 128; off > 0; off >>= 1) {
        if (tid < off) red[tid] += red[tid + off];
        __syncthreads();
    }

    const int wbase = wave * 128 - 64;
    const int rel0 = 3 * lane;
    const int s0 = wbase + rel0, s1 = s0 + 1, s2 = s0 + 2;

    const int i0 = (s0 >= 1 && s0 <= NS) ? seqs[b * NS + s0 - 1] : 0;
    const int i1 = (s1 >= 1 && s1 <= NS) ? seqs[b * NS + s1 - 1] : 0;
    const int i2 = (s2 >= 1 && s2 <= NS) ? seqs[b * NS + s2 - 1] : 0;
    const float* wrow0 = &wtabT[i0 * RSTRIDE];
    const float* wrow1 = &wtabT[i1 * RSTRIDE];
    const float* wrow2 = &wtabT[i2 * RSTRIDE];

    float p0 = (s0 == 0) ? 1.f : 0.f;
    float p1 = (s1 == 0) ? 1.f : 0.f;
    float p2 = (s2 == 0) ? 1.f : 0.f;
    float Lw  = 0.f;
    float adj = 1.f;

    __syncthreads();

    for (int c = 0; c < 125; ++c) {
        if (c > 0) {
            if ((c & 3) == 0) {
                __syncthreads();
                if (rel0     >= 64) Gbuf[64 + s0] = (p0 > 0.f) ? __builtin_amdgcn_logf(p0) + Lw : LOG0;
                if (rel0 + 1 >= 64) Gbuf[64 + s1] = (p1 > 0.f) ? __builtin_amdgcn_logf(p1) + Lw : LOG0;
                if (rel0 + 2 >= 64) Gbuf[64 + s2] = (p2 > 0.f) ? __builtin_amdgcn_logf(p2) + Lw : LOG0;
                __syncthreads();
                const float g0 = Gbuf[64 + s0];
                const float g1 = Gbuf[64 + s1];
                const float g2 = Gbuf[64 + s2];
                const float ref = fmaxf(fmaxf(g0, g1), g2);
                const bool alive = (ref > 0.5f * LOG0);
                int lastlive = alive ? lane : -1;
                #pragma unroll
                for (int o = 1; o < 64; o <<= 1) lastlive = max(lastlive, __shfl_xor(lastlive, o));
                float fb = __shfl(ref, (lastlive >= 0) ? lastlive : 0);
                if (lastlive < 0) fb = 0.f;
                Lw = alive ? ref : fb;
                p0 = __builtin_amdgcn_exp2f(g0 - Lw);
                p1 = __builtin_amdgcn_exp2f(g1 - Lw);
                p2 = __builtin_amdgcn_exp2f(g2 - Lw);
            } else {
                const float m = fmaxf(fmaxf(p0, p1), p2);
                if (m > 0.f) {
                    const float inv = __builtin_amdgcn_rcpf(m);
                    Lw += __builtin_amdgcn_logf(m);
                    p0 *= inv; p1 *= inv; p2 *= inv;
                }
            }
            const float Lwp = __shfl_up(Lw, 1);
            adj = __builtin_amdgcn_exp2f(fminf(Lwp - Lw, 100.f));
        }
        const int tb = c << 4;
        #pragma unroll
        for (int q = 0; q < 4; ++q) {
            const float4 wa = *reinterpret_cast<const float4*>(wrow0 + tb + 4 * q);
            const float4 wc4 = *reinterpret_cast<const float4*>(wrow1 + tb + 4 * q);
            const float4 wd = *reinterpret_cast<const float4*>(wrow2 + tb + 4 * q);
            STEP(wa.x, wc4.x, wd.x);
            STEP(wa.y, wc4.y, wd.y);
            STEP(wa.z, wc4.z, wd.z);
            STEP(wa.w, wc4.w, wd.w);
        }
    }

    __syncthreads();
    if (rel0     >= 64) Gbuf[64 + s0] = (p0 > 0.f) ? __builtin_amdgcn_logf(p0) + Lw : LOG0;
    if (rel0 + 1 >= 64) Gbuf[64 + s1] = (p1 > 0.f) ? __builtin_amdgcn_logf(p1) + Lw : LOG0;
    if (rel0 + 2 >= 64) Gbuf[64 + s2] = (p2 > 0.f) ? __builtin_amdgcn_logf(p2) + Lw : LOG0;
    __syncthreads();
    if (tid == 0) {
        const int sl = seqlens[b];
        out[b] = -(Gbuf[64 + sl] * LN2F + red[0]) * (1.0f / (float)NT);
    }
}

extern "C" void kernel_launch(void* const* d_in, const int* in_sizes, int n_in,
                              void* d_out, int out_size, void* d_ws, size_t ws_size,
                              hipStream_t stream) {
    const float* x       = (const float*)d_in[0];
    const int*   seqs    = (const int*)d_in[1];
    const int*   seqlens = (const int*)d_in[2];
    float*       out     = (float*)d_out;

    if (ws_size >= WS_NEEDED) {
        float* W    = (float*)d_ws;
        float* Csum = W + (size_t)NB * WBLK;
        prep_kernel<<<dim3(NB), dim3(256), 0, stream>>>(x, W, Csum);
        scan_kernel<<<dim3(NB), dim3(256), 0, stream>>>(W, Csum, seqs, seqlens, out);
    } else {
        ctc_fwd_fallback<<<dim3(NB), dim3(256), 0, stream>>>(x, seqs, seqlens, out);
    }
}

// Round 6
// 180.562 us; speedup vs baseline: 1.0788x; 1.0788x over previous
//
#include <hip/hip_runtime.h>

#define NT 2000
#define NB 256
#define NF 5
#define NS 500
#define LOG0   (-1e30f)
#define LOG2E  1.44269504088896340736f
#define LN2F   0.69314718055994530942f
#define RSTRIDE 2024   // row stride: %4==0 (b128 align), %32==8 (4 rows on disjoint banks)
#define MMIN   1e-37f  // renorm flush threshold: rcp(MMIN)=1e37 finite, log2 finite

// Cross-lane shift-up-by-1 via DPP wave_shr1 (0x138): lane n gets lane n-1,
// lane 0 gets 0. VALU-speed, no LDS pipe. (Semantics HW-verified in R4.)
__device__ __forceinline__ float shift_up1(float v) {
    int r = __builtin_amdgcn_update_dpp(0, __float_as_int(v), 0x138, 0xF, 0xF, false);
    return __int_as_float(r);
}

// One WAVE per batch (block = 64 threads, grid = 256 -> 1 block/CU).
// Lane L holds 8 adjacent states 8L..8L+7 in registers. Exp-domain recurrence
// p[s] += p[s-1] * w_t[idx[s]] with per-lane log2 scale Lw. No barriers in the
// 2000-step loop; only cross-lane traffic is one DPP shift per step.
// Renorm every 16 steps. Lanes whose max is below MMIN (>=123 log2 under their
// frame) are FLUSHED to exact zero and their Lw re-synced to the nearest live
// lane on the left -- this is the R1/R3-equivalent truncation and removes the
// rcp(denormal)=inf -> NaN path that killed R5.
__global__ __launch_bounds__(64) void ctc_fwd_kernel(
    const float* __restrict__ x,        // (NT, NB, NF)
    const int*   __restrict__ seqs,     // (NB, NS)
    const int*   __restrict__ seqlens,  // (NB,)
    float*       __restrict__ out)      // (NB,)
{
    __shared__ __align__(16) float wtabT[4 * RSTRIDE];  // w[i][t] = exp(x_t[i]-x_t[4])
    __shared__ float Gfin[512];                         // final log2-domain fwd

    const int b    = blockIdx.x;
    const int lane = threadIdx.x;   // 0..63

    // ---------------- prep: weight table (LDS) + stay-sum ----------------
    float csum = 0.f;
    for (int t = lane; t < NT; t += 64) {
        const float* xp = x + (size_t)t * (NB * NF) + b * NF;
        const float x4 = xp[4];
        wtabT[0 * RSTRIDE + t] = __builtin_amdgcn_exp2f((xp[0] - x4) * LOG2E);
        wtabT[1 * RSTRIDE + t] = __builtin_amdgcn_exp2f((xp[1] - x4) * LOG2E);
        wtabT[2 * RSTRIDE + t] = __builtin_amdgcn_exp2f((xp[2] - x4) * LOG2E);
        wtabT[3 * RSTRIDE + t] = __builtin_amdgcn_exp2f((xp[3] - x4) * LOG2E);
        csum += x4;
    }
    #pragma unroll
    for (int o = 32; o > 0; o >>= 1) csum += __shfl_xor(csum, o);
    // csum now wave-uniform = C = sum_t x_t[4]

    // Per-state move indices (state s uses seqs[b][s-1], s in 1..NS).
    const int sbase = 8 * lane;
    int idx[8];
    #pragma unroll
    for (int k = 0; k < 8; ++k) {
        const int s = sbase + k;
        idx[k] = (s >= 1 && s <= NS) ? seqs[b * NS + s - 1] : 0;
    }
    const float* r0 = &wtabT[idx[0] * RSTRIDE];
    const float* r1 = &wtabT[idx[1] * RSTRIDE];
    const float* r2 = &wtabT[idx[2] * RSTRIDE];
    const float* r3 = &wtabT[idx[3] * RSTRIDE];
    const float* r4 = &wtabT[idx[4] * RSTRIDE];
    const float* r5 = &wtabT[idx[5] * RSTRIDE];
    const float* r6 = &wtabT[idx[6] * RSTRIDE];
    const float* r7 = &wtabT[idx[7] * RSTRIDE];

    float p0 = (sbase == 0) ? 1.f : 0.f;   // state 0 lives in lane 0, reg 0
    float p1 = 0.f, p2 = 0.f, p3 = 0.f, p4 = 0.f, p5 = 0.f, p6 = 0.f, p7 = 0.f;
    float Lw  = 0.f;
    float adj = 1.f;

    __syncthreads();   // wtabT visible

#define SUBSTEP(C) do {                       \
        const float sh = shift_up1(p7);       \
        p7 = fmaf(p6, a7.C, p7);              \
        p6 = fmaf(p5, a6.C, p6);              \
        p5 = fmaf(p4, a5.C, p5);              \
        p4 = fmaf(p3, a4.C, p4);              \
        p3 = fmaf(p2, a3.C, p3);              \
        p2 = fmaf(p1, a2.C, p2);              \
        p1 = fmaf(p0, a1.C, p1);              \
        p0 = fmaf(sh * adj, a0.C, p0);        \
    } while (0)

    // ---------------- main loop: 125 chunks of 16 steps, zero barriers ----------------
    for (int c = 0; c < 125; ++c) {
        if (c > 0) {
            // per-lane renorm (flush-safe)
            const float m = fmaxf(fmaxf(fmaxf(p0, p1), fmaxf(p2, p3)),
                                  fmaxf(fmaxf(p4, p5), fmaxf(p6, p7)));
            const bool alive = (m > MMIN);
            if (alive) {
                const float inv = __builtin_amdgcn_rcpf(m);   // <= 1e37, finite
                Lw += __builtin_amdgcn_logf(m);               // v_log_f32 = log2, finite
                p0 *= inv; p1 *= inv; p2 *= inv; p3 *= inv;
                p4 *= inv; p5 *= inv; p6 *= inv; p7 *= inv;
            } else {
                // flush sub-threshold mass to exact zero (benign truncation,
                // same class as R1/R3); lane frame re-synced below
                p0 = 0.f; p1 = 0.f; p2 = 0.f; p3 = 0.f;
                p4 = 0.f; p5 = 0.f; p6 = 0.f; p7 = 0.f;
            }
            // dead lanes: Lw <- nearest live lane to the left (lane 0 always live)
            const unsigned long long mask  = __ballot(alive);
            const unsigned long long below = mask & ((lane < 63) ? ((2ULL << lane) - 1ULL) : ~0ULL);
            const int src = 63 - __builtin_clzll(below | 1ULL);
            Lw = __shfl(Lw, src);
            const float Lwp = __shfl_up(Lw, 1);
            adj = __builtin_amdgcn_exp2f(fminf(Lwp - Lw, 120.f));
        }
        const int tb = c << 4;
        #pragma unroll
        for (int q = 0; q < 4; ++q) {
            const int off = tb + 4 * q;
            const float4 a0 = *reinterpret_cast<const float4*>(r0 + off);
            const float4 a1 = *reinterpret_cast<const float4*>(r1 + off);
            const float4 a2 = *reinterpret_cast<const float4*>(r2 + off);
            const float4 a3 = *reinterpret_cast<const float4*>(r3 + off);
            const float4 a4 = *reinterpret_cast<const float4*>(r4 + off);
            const float4 a5 = *reinterpret_cast<const float4*>(r5 + off);
            const float4 a6 = *reinterpret_cast<const float4*>(r6 + off);
            const float4 a7 = *reinterpret_cast<const float4*>(r7 + off);
            SUBSTEP(x);
            SUBSTEP(y);
            SUBSTEP(z);
            SUBSTEP(w);
        }
    }
#undef SUBSTEP

    // ---------------- final write-out ----------------
    Gfin[sbase + 0] = (p0 > 0.f) ? __builtin_amdgcn_logf(p0) + Lw : LOG0;
    Gfin[sbase + 1] = (p1 > 0.f) ? __builtin_amdgcn_logf(p1) + Lw : LOG0;
    Gfin[sbase + 2] = (p2 > 0.f) ? __builtin_amdgcn_logf(p2) + Lw : LOG0;
    Gfin[sbase + 3] = (p3 > 0.f) ? __builtin_amdgcn_logf(p3) + Lw : LOG0;
    Gfin[sbase + 4] = (p4 > 0.f) ? __builtin_amdgcn_logf(p4) + Lw : LOG0;
    Gfin[sbase + 5] = (p5 > 0.f) ? __builtin_amdgcn_logf(p5) + Lw : LOG0;
    Gfin[sbase + 6] = (p6 > 0.f) ? __builtin_amdgcn_logf(p6) + Lw : LOG0;
    Gfin[sbase + 7] = (p7 > 0.f) ? __builtin_amdgcn_logf(p7) + Lw : LOG0;
    __syncthreads();
    if (lane == 0) {
        const int sl = seqlens[b];
        out[b] = -(Gfin[sl] * LN2F + csum) * (1.0f / (float)NT);
    }
}

extern "C" void kernel_launch(void* const* d_in, const int* in_sizes, int n_in,
                              void* d_out, int out_size, void* d_ws, size_t ws_size,
                              hipStream_t stream) {
    const float* x       = (const float*)d_in[0];
    const int*   seqs    = (const int*)d_in[1];
    const int*   seqlens = (const int*)d_in[2];
    float*       out     = (float*)d_out;

    ctc_fwd_kernel<<<dim3(NB), dim3(64), 0, stream>>>(x, seqs, seqlens, out);
}

// Round 7
// 173.755 us; speedup vs baseline: 1.1211x; 1.0392x over previous
//
#include <hip/hip_runtime.h>

#define NT 2000
#define NB 256
#define NF 5
#define NS 500
#define LOG0   (-1e30f)
#define LOG2E  1.44269504088896340736f
#define LN2F   0.69314718055994530942f
#define RSTRIDE 2024   // row stride: %4==0 (b128 align), %32==8 (4 rows on disjoint banks)
                       // also provides 24-float tail pad -> 2-ahead prefetch stays in-bounds
#define MMIN   1e-37f  // renorm flush threshold: rcp(MMIN)=1e37 finite, log2 finite

// Cross-lane shift-up-by-1 via DPP wave_shr1 (0x138): lane n gets lane n-1,
// lane 0 gets 0. VALU-speed, no LDS pipe. (HW-verified R4/R6.)
__device__ __forceinline__ float shift_up1(float v) {
    int r = __builtin_amdgcn_update_dpp(0, __float_as_int(v), 0x138, 0xF, 0xF, false);
    return __int_as_float(r);
}

// One WAVE per batch (block=64, grid=256 -> 1 block/CU). Lane L holds states
// 8L..8L+7 in registers; exp-domain recurrence with per-lane log2 scale
// (numerics identical to R6, which passed at absmax 0.00195).
// NEW in R7: weight reads are software-pipelined 2 q-groups (8 steps) ahead
// through a 4-buffer register rotation, hiding the ds_read latency that left
// R6 at 11.5% VALUBusy.
__global__ __launch_bounds__(64) void ctc_fwd_kernel(
    const float* __restrict__ x,        // (NT, NB, NF)
    const int*   __restrict__ seqs,     // (NB, NS)
    const int*   __restrict__ seqlens,  // (NB,)
    float*       __restrict__ out)      // (NB,)
{
    __shared__ __align__(16) float wtabT[4 * RSTRIDE];  // w[i][t] = exp(x_t[i]-x_t[4])
    __shared__ float Gfin[512];                         // final log2-domain fwd

    const int b    = blockIdx.x;
    const int lane = threadIdx.x;   // 0..63

    // ---------------- prep: weight table (LDS) + stay-sum ----------------
    float csum = 0.f;
    for (int t = lane; t < NT; t += 64) {
        const float* xp = x + (size_t)t * (NB * NF) + b * NF;
        const float x4 = xp[4];
        wtabT[0 * RSTRIDE + t] = __builtin_amdgcn_exp2f((xp[0] - x4) * LOG2E);
        wtabT[1 * RSTRIDE + t] = __builtin_amdgcn_exp2f((xp[1] - x4) * LOG2E);
        wtabT[2 * RSTRIDE + t] = __builtin_amdgcn_exp2f((xp[2] - x4) * LOG2E);
        wtabT[3 * RSTRIDE + t] = __builtin_amdgcn_exp2f((xp[3] - x4) * LOG2E);
        csum += x4;
    }
    #pragma unroll
    for (int o = 32; o > 0; o >>= 1) csum += __shfl_xor(csum, o);
    // csum wave-uniform = C = sum_t x_t[4]

    const int sbase = 8 * lane;
    int idx[8];
    #pragma unroll
    for (int k = 0; k < 8; ++k) {
        const int s = sbase + k;
        idx[k] = (s >= 1 && s <= NS) ? seqs[b * NS + s - 1] : 0;
    }
    const float* r0 = &wtabT[idx[0] * RSTRIDE];
    const float* r1 = &wtabT[idx[1] * RSTRIDE];
    const float* r2 = &wtabT[idx[2] * RSTRIDE];
    const float* r3 = &wtabT[idx[3] * RSTRIDE];
    const float* r4 = &wtabT[idx[4] * RSTRIDE];
    const float* r5 = &wtabT[idx[5] * RSTRIDE];
    const float* r6 = &wtabT[idx[6] * RSTRIDE];
    const float* r7 = &wtabT[idx[7] * RSTRIDE];

    float p0 = (sbase == 0) ? 1.f : 0.f;
    float p1 = 0.f, p2 = 0.f, p3 = 0.f, p4 = 0.f, p5 = 0.f, p6 = 0.f, p7 = 0.f;
    float Lw  = 0.f;
    float adj = 1.f;

    __syncthreads();   // wtabT visible

    // 4 rotating prefetch buffers, 8 float4 each (constant indices -> VGPRs)
    float4 A[8], B[8], C[8], D[8];

#define LOADQ(BUF, off) do {                                        \
        BUF[0] = *reinterpret_cast<const float4*>(r0 + (off));      \
        BUF[1] = *reinterpret_cast<const float4*>(r1 + (off));      \
        BUF[2] = *reinterpret_cast<const float4*>(r2 + (off));      \
        BUF[3] = *reinterpret_cast<const float4*>(r3 + (off));      \
        BUF[4] = *reinterpret_cast<const float4*>(r4 + (off));      \
        BUF[5] = *reinterpret_cast<const float4*>(r5 + (off));      \
        BUF[6] = *reinterpret_cast<const float4*>(r6 + (off));      \
        BUF[7] = *reinterpret_cast<const float4*>(r7 + (off));      \
    } while (0)

#define SUBSTEP(BUF, COMP) do {                   \
        const float sh = shift_up1(p7);           \
        p7 = fmaf(p6, BUF[7].COMP, p7);           \
        p6 = fmaf(p5, BUF[6].COMP, p6);           \
        p5 = fmaf(p4, BUF[5].COMP, p5);           \
        p4 = fmaf(p3, BUF[4].COMP, p4);           \
        p3 = fmaf(p2, BUF[3].COMP, p3);           \
        p2 = fmaf(p1, BUF[2].COMP, p2);           \
        p1 = fmaf(p0, BUF[1].COMP, p1);           \
        p0 = fmaf(sh * adj, BUF[0].COMP, p0);     \
    } while (0)

#define COMPQ(BUF) do { SUBSTEP(BUF, x); SUBSTEP(BUF, y); SUBSTEP(BUF, z); SUBSTEP(BUF, w); } while (0)

    // prologue: q-groups 0 and 1 in flight / resident
    LOADQ(A, 0);
    LOADQ(B, 4);

    // ---------------- main loop: 125 chunks x 16 steps ----------------
    for (int c = 0; c < 125; ++c) {
        if (c > 0) {
            // per-lane renorm (flush-safe) -- identical to R6
            const float m = fmaxf(fmaxf(fmaxf(p0, p1), fmaxf(p2, p3)),
                                  fmaxf(fmaxf(p4, p5), fmaxf(p6, p7)));
            const bool alive = (m > MMIN);
            if (alive) {
                const float inv = __builtin_amdgcn_rcpf(m);
                Lw += __builtin_amdgcn_logf(m);
                p0 *= inv; p1 *= inv; p2 *= inv; p3 *= inv;
                p4 *= inv; p5 *= inv; p6 *= inv; p7 *= inv;
            } else {
                p0 = 0.f; p1 = 0.f; p2 = 0.f; p3 = 0.f;
                p4 = 0.f; p5 = 0.f; p6 = 0.f; p7 = 0.f;
            }
            const unsigned long long mask  = __ballot(alive);
            const unsigned long long below = mask & ((lane < 63) ? ((2ULL << lane) - 1ULL) : ~0ULL);
            const int src = 63 - __builtin_clzll(below | 1ULL);
            Lw = __shfl(Lw, src);
            const float Lwp = __shfl_up(Lw, 1);
            adj = __builtin_amdgcn_exp2f(fminf(Lwp - Lw, 120.f));
        }
        const int tb = c << 4;
        // rotation: compute A,B,C,D while loading 2 groups ahead.
        // At c=124 the +16/+20 prefetches read the RSTRIDE tail pad
        // (in-bounds, values unused).
        LOADQ(C, tb + 8);   COMPQ(A);
        LOADQ(D, tb + 12);  COMPQ(B);
        LOADQ(A, tb + 16);  COMPQ(C);
        LOADQ(B, tb + 20);  COMPQ(D);
    }
#undef COMPQ
#undef SUBSTEP
#undef LOADQ

    // ---------------- final write-out ----------------
    Gfin[sbase + 0] = (p0 > 0.f) ? __builtin_amdgcn_logf(p0) + Lw : LOG0;
    Gfin[sbase + 1] = (p1 > 0.f) ? __builtin_amdgcn_logf(p1) + Lw : LOG0;
    Gfin[sbase + 2] = (p2 > 0.f) ? __builtin_amdgcn_logf(p2) + Lw : LOG0;
    Gfin[sbase + 3] = (p3 > 0.f) ? __builtin_amdgcn_logf(p3) + Lw : LOG0;
    Gfin[sbase + 4] = (p4 > 0.f) ? __builtin_amdgcn_logf(p4) + Lw : LOG0;
    Gfin[sbase + 5] = (p5 > 0.f) ? __builtin_amdgcn_logf(p5) + Lw : LOG0;
    Gfin[sbase + 6] = (p6 > 0.f) ? __builtin_amdgcn_logf(p6) + Lw : LOG0;
    Gfin[sbase + 7] = (p7 > 0.f) ? __builtin_amdgcn_logf(p7) + Lw : LOG0;
    __syncthreads();
    if (lane == 0) {
        const int sl = seqlens[b];
        out[b] = -(Gfin[sl] * LN2F + csum) * (1.0f / (float)NT);
    }
}

extern "C" void kernel_launch(void* const* d_in, const int* in_sizes, int n_in,
                              void* d_out, int out_size, void* d_ws, size_t ws_size,
                              hipStream_t stream) {
    const float* x       = (const float*)d_in[0];
    const int*   seqs    = (const int*)d_in[1];
    const int*   seqlens = (const int*)d_in[2];
    float*       out     = (float*)d_out;

    ctc_fwd_kernel<<<dim3(NB), dim3(64), 0, stream>>>(x, seqs, seqlens, out);
}

// Round 8
// 173.745 us; speedup vs baseline: 1.1212x; 1.0001x over previous
//
#include <hip/hip_runtime.h>

#define NT 2000
#define NB 256
#define NF 5
#define NS 500
#define LOG0   (-1e30f)
#define LOG2E  1.44269504088896340736f
#define LN2F   0.69314718055994530942f
#define RSTRIDE 2024   // row stride: %4==0 (b128 align), %32==8 (4 rows on disjoint banks)
                       // also provides 24-float tail pad -> 2-ahead prefetch stays in-bounds
#define MMIN   1e-37f  // renorm flush threshold: rcp(MMIN)=1e37 finite, log2 finite

// Cross-lane shift-up-by-1 via DPP wave_shr1 (0x138): lane n gets lane n-1,
// lane 0 gets 0. VALU-speed, no LDS pipe. (HW-verified R4/R6.)
__device__ __forceinline__ float shift_up1(float v) {
    int r = __builtin_amdgcn_update_dpp(0, __float_as_int(v), 0x138, 0xF, 0xF, false);
    return __int_as_float(r);
}

// One WAVE per batch (block=64, grid=256 -> 1 block/CU). Lane L holds states
// 8L..8L+7 in registers; exp-domain recurrence with per-lane log2 scale
// (numerics identical to R6/R7, absmax 0.00195).
// R8: (a) __launch_bounds__(64,1) so the 4 rotating prefetch buffers (128
// VGPRs) actually fit in registers -- R7's 132-VGPR clamp demoted the
// pipeline; (b) prefetch groups issued in two 4-load halves between SUBSTEPs
// to keep outstanding LDS ops within the 4-bit lgkmcnt tracking range.
__global__ __launch_bounds__(64, 1) void ctc_fwd_kernel(
    const float* __restrict__ x,        // (NT, NB, NF)
    const int*   __restrict__ seqs,     // (NB, NS)
    const int*   __restrict__ seqlens,  // (NB,)
    float*       __restrict__ out)      // (NB,)
{
    __shared__ __align__(16) float wtabT[4 * RSTRIDE];  // w[i][t] = exp(x_t[i]-x_t[4])
    __shared__ float Gfin[512];                         // final log2-domain fwd

    const int b    = blockIdx.x;
    const int lane = threadIdx.x;   // 0..63

    // ---------------- prep: weight table (LDS) + stay-sum ----------------
    float csum = 0.f;
    for (int t = lane; t < NT; t += 64) {
        const float* xp = x + (size_t)t * (NB * NF) + b * NF;
        const float x4 = xp[4];
        wtabT[0 * RSTRIDE + t] = __builtin_amdgcn_exp2f((xp[0] - x4) * LOG2E);
        wtabT[1 * RSTRIDE + t] = __builtin_amdgcn_exp2f((xp[1] - x4) * LOG2E);
        wtabT[2 * RSTRIDE + t] = __builtin_amdgcn_exp2f((xp[2] - x4) * LOG2E);
        wtabT[3 * RSTRIDE + t] = __builtin_amdgcn_exp2f((xp[3] - x4) * LOG2E);
        csum += x4;
    }
    #pragma unroll
    for (int o = 32; o > 0; o >>= 1) csum += __shfl_xor(csum, o);
    // csum wave-uniform = C = sum_t x_t[4]

    const int sbase = 8 * lane;
    int idx[8];
    #pragma unroll
    for (int k = 0; k < 8; ++k) {
        const int s = sbase + k;
        idx[k] = (s >= 1 && s <= NS) ? seqs[b * NS + s - 1] : 0;
    }
    const float* r0 = &wtabT[idx[0] * RSTRIDE];
    const float* r1 = &wtabT[idx[1] * RSTRIDE];
    const float* r2 = &wtabT[idx[2] * RSTRIDE];
    const float* r3 = &wtabT[idx[3] * RSTRIDE];
    const float* r4 = &wtabT[idx[4] * RSTRIDE];
    const float* r5 = &wtabT[idx[5] * RSTRIDE];
    const float* r6 = &wtabT[idx[6] * RSTRIDE];
    const float* r7 = &wtabT[idx[7] * RSTRIDE];

    float p0 = (sbase == 0) ? 1.f : 0.f;
    float p1 = 0.f, p2 = 0.f, p3 = 0.f, p4 = 0.f, p5 = 0.f, p6 = 0.f, p7 = 0.f;
    float Lw  = 0.f;
    float adj = 1.f;

    __syncthreads();   // wtabT visible

    // 4 rotating prefetch buffers, 8 float4 each (constant indices -> VGPRs)
    float4 A[8], B[8], C[8], D[8];

#define LOADH1(BUF, off) do {                                       \
        BUF[0] = *reinterpret_cast<const float4*>(r0 + (off));      \
        BUF[1] = *reinterpret_cast<const float4*>(r1 + (off));      \
        BUF[2] = *reinterpret_cast<const float4*>(r2 + (off));      \
        BUF[3] = *reinterpret_cast<const float4*>(r3 + (off));      \
    } while (0)
#define LOADH2(BUF, off) do {                                       \
        BUF[4] = *reinterpret_cast<const float4*>(r4 + (off));      \
        BUF[5] = *reinterpret_cast<const float4*>(r5 + (off));      \
        BUF[6] = *reinterpret_cast<const float4*>(r6 + (off));      \
        BUF[7] = *reinterpret_cast<const float4*>(r7 + (off));      \
    } while (0)

#define SUBSTEP(BUF, COMP) do {                   \
        const float sh = shift_up1(p7);           \
        p7 = fmaf(p6, BUF[7].COMP, p7);           \
        p6 = fmaf(p5, BUF[6].COMP, p6);           \
        p5 = fmaf(p4, BUF[5].COMP, p5);           \
        p4 = fmaf(p3, BUF[4].COMP, p4);           \
        p3 = fmaf(p2, BUF[3].COMP, p3);           \
        p2 = fmaf(p1, BUF[2].COMP, p2);           \
        p1 = fmaf(p0, BUF[1].COMP, p1);           \
        p0 = fmaf(sh * adj, BUF[0].COMP, p0);     \
    } while (0)

    // Compute 4 steps on CUR while issuing the two halves of NXT's loads
    // (2 groups ahead) between step pairs.
#define GROUP(CUR, NXT, nxt_off) do {             \
        LOADH1(NXT, (nxt_off));                   \
        SUBSTEP(CUR, x);                          \
        SUBSTEP(CUR, y);                          \
        LOADH2(NXT, (nxt_off));                   \
        SUBSTEP(CUR, z);                          \
        SUBSTEP(CUR, w);                          \
    } while (0)

    // prologue: q-groups 0 and 1 in flight / resident
    LOADH1(A, 0); LOADH2(A, 0);
    LOADH1(B, 4); LOADH2(B, 4);

    // ---------------- main loop: 125 chunks x 16 steps ----------------
    for (int c = 0; c < 125; ++c) {
        if (c > 0) {
            // per-lane renorm (flush-safe) -- identical to R6/R7
            const float m = fmaxf(fmaxf(fmaxf(p0, p1), fmaxf(p2, p3)),
                                  fmaxf(fmaxf(p4, p5), fmaxf(p6, p7)));
            const bool alive = (m > MMIN);
            if (alive) {
                const float inv = __builtin_amdgcn_rcpf(m);
                Lw += __builtin_amdgcn_logf(m);
                p0 *= inv; p1 *= inv; p2 *= inv; p3 *= inv;
                p4 *= inv; p5 *= inv; p6 *= inv; p7 *= inv;
            } else {
                p0 = 0.f; p1 = 0.f; p2 = 0.f; p3 = 0.f;
                p4 = 0.f; p5 = 0.f; p6 = 0.f; p7 = 0.f;
            }
            const unsigned long long mask  = __ballot(alive);
            const unsigned long long below = mask & ((lane < 63) ? ((2ULL << lane) - 1ULL) : ~0ULL);
            const int src = 63 - __builtin_clzll(below | 1ULL);
            Lw = __shfl(Lw, src);
            const float Lwp = __shfl_up(Lw, 1);
            adj = __builtin_amdgcn_exp2f(fminf(Lwp - Lw, 120.f));
        }
        const int tb = c << 4;
        // rotation: compute A,B,C,D while loading 2 groups ahead.
        // At c=124 the +16/+20 prefetches read the RSTRIDE tail pad
        // (in-bounds, values unused).
        GROUP(A, C, tb + 8);
        GROUP(B, D, tb + 12);
        GROUP(C, A, tb + 16);
        GROUP(D, B, tb + 20);
    }
#undef GROUP
#undef SUBSTEP
#undef LOADH1
#undef LOADH2

    // ---------------- final write-out ----------------
    Gfin[sbase + 0] = (p0 > 0.f) ? __builtin_amdgcn_logf(p0) + Lw : LOG0;
    Gfin[sbase + 1] = (p1 > 0.f) ? __builtin_amdgcn_logf(p1) + Lw : LOG0;
    Gfin[sbase + 2] = (p2 > 0.f) ? __builtin_amdgcn_logf(p2) + Lw : LOG0;
    Gfin[sbase + 3] = (p3 > 0.f) ? __builtin_amdgcn_logf(p3) + Lw : LOG0;
    Gfin[sbase + 4] = (p4 > 0.f) ? __builtin_amdgcn_logf(p4) + Lw : LOG0;
    Gfin[sbase + 5] = (p5 > 0.f) ? __builtin_amdgcn_logf(p5) + Lw : LOG0;
    Gfin[sbase + 6] = (p6 > 0.f) ? __builtin_amdgcn_logf(p6) + Lw : LOG0;
    Gfin[sbase + 7] = (p7 > 0.f) ? __builtin_amdgcn_logf(p7) + Lw : LOG0;
    __syncthreads();
    if (lane == 0) {
        const int sl = seqlens[b];
        out[b] = -(Gfin[sl] * LN2F + csum) * (1.0f / (float)NT);
    }
}

extern "C" void kernel_launch(void* const* d_in, const int* in_sizes, int n_in,
                              void* d_out, int out_size, void* d_ws, size_t ws_size,
                              hipStream_t stream) {
    const float* x       = (const float*)d_in[0];
    const int*   seqs    = (const int*)d_in[1];
    const int*   seqlens = (const int*)d_in[2];
    float*       out     = (float*)d_out;

    ctc_fwd_kernel<<<dim3(NB), dim3(64), 0, stream>>>(x, seqs, seqlens, out);
}